// Round 9
// baseline (922.239 us; speedup 1.0000x reference)
//
#include <hip/hip_runtime.h>
#include <math.h>

#define BB 4
#define UU 512
#define DD 80
#define HH 8
#define FFND 2048
#define LL 12
#define SEGC 32
#define LCC 50
#define RCC 8
#define NSEG 16
#define RCL 128
#define KK 640
#define ROWS (BB*KK)        // 2560
#define OUTD 768
#define EPSF 1e-5f
#define SCALEF 0.31622776601683794f  // (D/H)^-0.5

typedef __attribute__((ext_vector_type(8))) short bf16x8;
typedef __attribute__((ext_vector_type(4))) float f32x4;

__device__ inline unsigned short f2bf(float f) {
  unsigned int u = __float_as_uint(f);
  u += 0x7fffu + ((u >> 16) & 1u);
  return (unsigned short)(u >> 16);
}

// ---------------- gather: x0 = concat(rc, utt) ----------------
__global__ __launch_bounds__(256) void k_gather(const float* __restrict__ mel,
                                                float* __restrict__ x) {
  int idx = blockIdx.x * 256 + threadIdx.x;
  if (idx >= ROWS * DD) return;
  int d = idx % DD;
  int row = idx / DD;
  int b = row / KK;
  int j = row % KK;
  int pos;
  if (j < RCL) {
    int i = j >> 3, r = j & 7;
    pos = (i < NSEG - 1) ? (i + 1) * SEGC + r : UU + r;
  } else {
    pos = j - RCL;
  }
  x[idx] = mel[(b * (UU + RCC) + pos) * DD + d];
}

// ---------------- convert W1/W2 (all layers) fp32 -> bf16 ----------------
__global__ __launch_bounds__(256) void k_cvt(const float* __restrict__ W1,
                                             const float* __restrict__ W2,
                                             unsigned short* __restrict__ o1,
                                             unsigned short* __restrict__ o2) {
  const int NV = (LL * FFND * DD) / 4;
  int t = blockIdx.x * 256 + threadIdx.x;
  const float* src;
  unsigned short* dst;
  int i;
  if (t < NV) { src = W1; dst = o1; i = t; }
  else        { src = W2; dst = o2; i = t - NV; }
  float4 v = reinterpret_cast<const float4*>(src)[i];
  ushort4 r;
  r.x = f2bf(v.x); r.y = f2bf(v.y); r.z = f2bf(v.z); r.w = f2bf(v.w);
  reinterpret_cast<ushort4*>(dst)[i] = r;
}

// ---------------- A: LN_in fused + QKV GEMM (layer 0 only) ----------------
__global__ __launch_bounds__(256) void k_qkv(
    const float* __restrict__ x, float* __restrict__ qkv,
    const float* __restrict__ Wq, const float* __restrict__ bq,
    const float* __restrict__ Wkv, const float* __restrict__ bkv,
    const float* __restrict__ lg, const float* __restrict__ lb) {
  __shared__ float s_x[32 * 84];
  __shared__ float s_w[80 * 84];
  __shared__ float s_mu[32], s_ri[32];
  int tid = threadIdx.x;
  int r0 = blockIdx.x * 32;
  int ct = blockIdx.y;
  for (int k = 0; k < 3; ++k) {
    int idx = tid + k * 256;
    if (idx < 640) {
      int row = idx / 20, c4 = idx % 20;
      *reinterpret_cast<float4*>(&s_x[row * 84 + c4 * 4]) =
          *reinterpret_cast<const float4*>(&x[(r0 + row) * DD + c4 * 4]);
    }
  }
  const float* Wbase = (ct == 0) ? Wq : (ct == 1 ? Wkv : (Wkv + 80 * DD));
  for (int k = 0; k < 7; ++k) {
    int idx = tid + k * 256;
    if (idx < 1600) {
      int c = idx / 20, d4 = idx % 20;
      *reinterpret_cast<float4*>(&s_w[c * 84 + d4 * 4]) =
          *reinterpret_cast<const float4*>(&Wbase[c * DD + d4 * 4]);
    }
  }
  __syncthreads();
  {
    int rr = tid >> 3, t8 = tid & 7;
    float sm = 0.f, sq = 0.f;
    for (int d = t8 * 10; d < t8 * 10 + 10; ++d) {
      float v = s_x[rr * 84 + d];
      sm += v; sq += v * v;
    }
    for (int m = 4; m >= 1; m >>= 1) {
      sm += __shfl_xor(sm, m, 8);
      sq += __shfl_xor(sq, m, 8);
    }
    if (t8 == 0) {
      float mu = sm * (1.f / DD);
      s_mu[rr] = mu;
      s_ri[rr] = rsqrtf(sq * (1.f / DD) - mu * mu + EPSF);
    }
  }
  __syncthreads();
  for (int k = 0; k < 10; ++k) {
    int e = tid + k * 256;
    int row = e / 80, d = e % 80;
    s_x[row * 84 + d] = (s_x[row * 84 + d] - s_mu[row]) * s_ri[row] * lg[d] + lb[d];
  }
  __syncthreads();
  int ty = tid >> 4, tx = tid & 15;
  float acc[2][5] = {};
  for (int d4 = 0; d4 < 20; ++d4) {
    float4 a0 = *reinterpret_cast<const float4*>(&s_x[(2 * ty) * 84 + d4 * 4]);
    float4 a1 = *reinterpret_cast<const float4*>(&s_x[(2 * ty + 1) * 84 + d4 * 4]);
#pragma unroll
    for (int j = 0; j < 5; ++j) {
      float4 w = *reinterpret_cast<const float4*>(&s_w[(tx + 16 * j) * 84 + d4 * 4]);
      acc[0][j] += a0.x * w.x + a0.y * w.y + a0.z * w.z + a0.w * w.w;
      acc[1][j] += a1.x * w.x + a1.y * w.y + a1.z * w.z + a1.w * w.w;
    }
  }
  const float* bias = (ct == 0) ? bq : (bkv + (ct == 2 ? 80 : 0));
  for (int i2 = 0; i2 < 2; ++i2)
    for (int j = 0; j < 5; ++j) {
      int c = tx + 16 * j;
      int grow = r0 + 2 * ty + i2;
      qkv[grow * 240 + ct * 80 + c] = acc[i2][j] + bias[c];
    }
}

// ---------------- B: masked segmented attention ----------------
__global__ __launch_bounds__(256) void k_attn(const float* __restrict__ qkv,
                                              float* __restrict__ attn,
                                              const int* __restrict__ lengths) {
  int i = blockIdx.x, h = blockIdx.y, b = blockIdx.z;
  int tid = threadIdx.x;
  int s = i * SEGC - LCC; if (s < 0) s = 0;
  int e = (i + 1) * SEGC;
  int nk = RCC + (e - s);  // <= 90
  __shared__ float s_k[90 * 10], s_v[90 * 10], s_q[40 * 10];
  __shared__ float s_p[40 * 90], s_kb[90], s_den[40];
  int len = lengths[b];
  if (tid < 90 && tid < nk) {
    int j = tid;
    int kr = (j < RCC) ? i * RCC + j : RCL + s + (j - RCC);
    const float* kp = &qkv[(b * KK + kr) * 240 + 80 + h * 10];
    const float* vp = &qkv[(b * KK + kr) * 240 + 160 + h * 10];
#pragma unroll
    for (int d = 0; d < 10; ++d) { s_k[j * 10 + d] = kp[d]; s_v[j * 10 + d] = vp[d]; }
    s_kb[j] = (kr >= len + RCL) ? -1e8f : 0.f;
  }
  if (tid >= 128 && tid < 168) {
    int j = tid - 128;
    int qr = (j < RCC) ? i * RCC + j : RCL + i * SEGC + (j - RCC);
    const float* qp = &qkv[(b * KK + qr) * 240 + h * 10];
#pragma unroll
    for (int d = 0; d < 10; ++d) s_q[j * 10 + d] = qp[d];
  }
  __syncthreads();
  for (int p = tid; p < 3600; p += 256) {
    int q = p / 90, jk = p % 90;
    float sc = -1e30f;
    if (jk < nk) {
      float dot = 0.f;
#pragma unroll
      for (int d = 0; d < 10; ++d) dot += s_q[q * 10 + d] * s_k[jk * 10 + d];
      sc = dot * SCALEF + s_kb[jk];
    }
    s_p[p] = sc;
  }
  __syncthreads();
  if (tid < 160) {
    int r = tid >> 2, l4 = tid & 3;
    float m = -1e30f;
    for (int kx = l4; kx < 90; kx += 4) m = fmaxf(m, s_p[r * 90 + kx]);
    m = fmaxf(m, __shfl_xor(m, 1, 4));
    m = fmaxf(m, __shfl_xor(m, 2, 4));
    float sum = 0.f;
    for (int kx = l4; kx < 90; kx += 4) {
      float ev = __expf(s_p[r * 90 + kx] - m);
      s_p[r * 90 + kx] = ev;
      sum += ev;
    }
    sum += __shfl_xor(sum, 1, 4);
    sum += __shfl_xor(sum, 2, 4);
    if (l4 == 0) s_den[r] = sum;
  }
  __syncthreads();
  for (int po = tid; po < 400; po += 256) {
    int q = po / 10, d = po % 10;
    float o = 0.f;
    for (int kx = 0; kx < 90; ++kx) o += s_p[q * 90 + kx] * s_v[kx * 10 + d];
    int qr = (q < RCC) ? i * RCC + q : RCL + i * SEGC + (q - RCC);
    attn[(b * KK + qr) * DD + h * 10 + d] = o / s_den[q];
  }
}

// --- fused: OPROJ + LN_ff + full-K FFN + b2/residual/LN_out + QKV(l+1) ---
// grid 256 x 10 rows, block 256. FFN weight staging is WAVE-PRIVATE:
// wave w stages+reads only W1 rows [w*32,w*32+32) and W2 k-cols
// [w*32,w*32+32) -> the 16-chunk loop has NO barriers; the 4 waves drift
// and overlap each other's L2 latency. Prefetch 1 chunk ahead in regs.
__global__ __launch_bounds__(256) void k_fused(
    const float* __restrict__ attn, float* __restrict__ x,
    float* __restrict__ qkv,
    const float* __restrict__ Wo, const float* __restrict__ bo,
    const float* __restrict__ ffg, const float* __restrict__ ffb,
    const unsigned short* __restrict__ W1l, const float* __restrict__ b1l,
    const unsigned short* __restrict__ W2l, const float* __restrict__ b2l,
    const float* __restrict__ ogl, const float* __restrict__ obl,
    const float* __restrict__ lng_n, const float* __restrict__ lnb_n,
    const float* __restrict__ Wq_n, const float* __restrict__ bq_n,
    const float* __restrict__ Wkv_n, const float* __restrict__ bkv_n,
    int do_qkv) {
  __shared__ __align__(16) char smraw[64512];
  // layout (bytes):
  //   [0,3328)       s_fa   16x104 bf16 (A tile, K-pad)
  //   [3328,29952)   s_w1w  4 waves x 32x104 bf16 (wave-private W1 slice)
  //   [29952,55552)  s_w2w  4 waves x 80x40  bf16 (wave-private W2 slice)
  //   [55552,61184)  s_h    4 waves x 16x44  bf16 (pad 44 kills q-collision)
  //   [61184,64384)  s_res  10x80 f32
  //   [64384,64512)  s_mu2/s_ri2
  // aliases (dead-region reuse, barrier-separated):
  //   oproj: s_at@3328, s_x2@6688, s_wo@10048 (f32)
  //   epilogue: s_red@3328 (4x16x80 f32), s_val@29952 (800 f32)
  unsigned short* s_fa = (unsigned short*)smraw;
  float* s_res = (float*)(smraw + 61184);
  float* s_at  = (float*)(smraw + 3328);
  float* s_x2  = (float*)(smraw + 6688);
  float* s_wo  = (float*)(smraw + 10048);
  float* s_red = (float*)(smraw + 3328);
  float* s_val = (float*)(smraw + 29952);
  float* s_mu2 = (float*)(smraw + 64384);
  float* s_ri2 = (float*)(smraw + 64448);
  int tid = threadIdx.x;
  int r0 = blockIdx.x * 10;
  int w = tid >> 6, lane = tid & 63, m = lane & 15, q = lane >> 4;
  unsigned short* s_w1w = (unsigned short*)(smraw + 3328) + w * 3328;   // 32x104
  unsigned short* s_w2w = (unsigned short*)(smraw + 29952) + w * 3200;  // 80x40
  unsigned short* s_hw  = (unsigned short*)(smraw + 55552) + w * 704;   // 16x44
  // zero s_fa (rows 10..15 and cols 80..103 stay zero = K-pad)
  if (tid < 208) {
    int row = tid / 13, ch = tid % 13;
    *reinterpret_cast<uint4*>(&s_fa[row * 104 + ch * 8]) = make_uint4(0, 0, 0, 0);
  }
  // stage attn + x rows (10 x 20 float4)
  if (tid < 200) {
    int row = tid / 20, c4 = tid % 20;
    *reinterpret_cast<float4*>(&s_at[row * 84 + c4 * 4]) =
        *reinterpret_cast<const float4*>(&attn[(r0 + row) * DD + c4 * 4]);
    *reinterpret_cast<float4*>(&s_x2[row * 84 + c4 * 4]) =
        *reinterpret_cast<const float4*>(&x[(r0 + row) * DD + c4 * 4]);
  }
  for (int k = 0; k < 7; ++k) {
    int idx = tid + k * 256;
    if (idx < 1600) {
      int c = idx / 20, d4 = idx % 20;
      *reinterpret_cast<float4*>(&s_wo[c * 84 + d4 * 4]) =
          *reinterpret_cast<const float4*>(&Wo[c * DD + d4 * 4]);
    }
  }
  __syncthreads();
  // oproj + bias + residual + LN_ff -> s_fa (bf16), s_res
  if (tid < 160) {
    int r = tid >> 4, tx = tid & 15;
    float acc[5] = {};
    for (int d4 = 0; d4 < 20; ++d4) {
      float4 a = *reinterpret_cast<const float4*>(&s_at[r * 84 + d4 * 4]);
#pragma unroll
      for (int j = 0; j < 5; ++j) {
        float4 ww = *reinterpret_cast<const float4*>(&s_wo[(tx + 16 * j) * 84 + d4 * 4]);
        acc[j] += a.x * ww.x + a.y * ww.y + a.z * ww.z + a.w * ww.w;
      }
    }
    float val[5];
    float sm = 0.f, sq = 0.f;
#pragma unroll
    for (int j = 0; j < 5; ++j) {
      int c = tx + 16 * j;
      float v = acc[j] + bo[c] + s_x2[r * 84 + c];
      val[j] = v;
      s_res[r * 80 + c] = v;
      sm += v; sq += v * v;
    }
    for (int mm = 8; mm >= 1; mm >>= 1) {
      sm += __shfl_xor(sm, mm, 16);
      sq += __shfl_xor(sq, mm, 16);
    }
    float mu = sm * (1.f / DD);
    float ri = rsqrtf(sq * (1.f / DD) - mu * mu + EPSF);
#pragma unroll
    for (int j = 0; j < 5; ++j) {
      int c = tx + 16 * j;
      s_fa[r * 104 + c] = f2bf((val[j] - mu) * ri * ffg[c] + ffb[c]);
    }
  }
  __syncthreads();  // s_fa/s_res ready; s_at/s_x2/s_wo dead
  // zero K-pad cols 80..95 of this wave's W1 slice (staging never writes them)
  {
    int row = lane >> 1, half = lane & 1;
    uint4 z = make_uint4(0, 0, 0, 0);
    *reinterpret_cast<uint4*>(&s_w1w[row * 104 + 80 + half * 8]) = z;
  }
  // prefetch chunk 0 (wave-private slices; 5+5 uint4 per lane)
  uint4 rw1[5], rw2[5];
#pragma unroll
  for (int k = 0; k < 5; ++k) {
    int idx = lane + k * 64;            // 320 = 32 rows x 10 chunks
    int row1 = idx / 10, ch1 = idx % 10;
    rw1[k] = *reinterpret_cast<const uint4*>(&W1l[(w * 32 + row1) * DD + ch1 * 8]);
  }
#pragma unroll
  for (int k = 0; k < 5; ++k) {
    int idx = lane + k * 64;            // 320 = 80 rows x 4 chunks
    int row2 = idx >> 2, ch2 = idx & 3;
    rw2[k] = *reinterpret_cast<const uint4*>(&W2l[row2 * FFND + w * 32 + ch2 * 8]);
  }
  f32x4 acc2[5] = {};
  for (int c = 0; c < 16; ++c) {
    int fc0 = c * 128;
    // write staged regs to own LDS slices (same-wave DS ops are in-order:
    // prior chunk's reads of these addresses complete first; no barrier)
#pragma unroll
    for (int k = 0; k < 5; ++k) {
      int idx = lane + k * 64;
      int row1 = idx / 10, ch1 = idx % 10;
      *reinterpret_cast<uint4*>(&s_w1w[row1 * 104 + ch1 * 8]) = rw1[k];
    }
#pragma unroll
    for (int k = 0; k < 5; ++k) {
      int idx = lane + k * 64;
      int row2 = idx >> 2, ch2 = idx & 3;
      *reinterpret_cast<uint4*>(&s_w2w[row2 * 40 + ch2 * 8]) = rw2[k];
    }
    if (c < 15) {  // issue next chunk loads; latency hides under MFMA + waves
      int fn = fc0 + 128;
#pragma unroll
      for (int k = 0; k < 5; ++k) {
        int idx = lane + k * 64;
        int row1 = idx / 10, ch1 = idx % 10;
        rw1[k] = *reinterpret_cast<const uint4*>(&W1l[(fn + w * 32 + row1) * DD + ch1 * 8]);
      }
#pragma unroll
      for (int k = 0; k < 5; ++k) {
        int idx = lane + k * 64;
        int row2 = idx >> 2, ch2 = idx & 3;
        rw2[k] = *reinterpret_cast<const uint4*>(&W2l[row2 * FFND + fn + w * 32 + ch2 * 8]);
      }
    }
    // FFN1: wave w owns ffn cols [fc0+w*32, fc0+w*32+32)
    f32x4 acc1[2] = {};
#pragma unroll
    for (int kk = 0; kk < 3; ++kk) {
      bf16x8 a = *reinterpret_cast<const bf16x8*>(&s_fa[m * 104 + kk * 32 + q * 8]);
#pragma unroll
      for (int ct2 = 0; ct2 < 2; ++ct2) {
        bf16x8 b = *reinterpret_cast<const bf16x8*>(
            &s_w1w[(ct2 * 16 + m) * 104 + kk * 32 + q * 8]);
        acc1[ct2] = __builtin_amdgcn_mfma_f32_16x16x32_bf16(a, b, acc1[ct2], 0, 0, 0);
      }
    }
#pragma unroll
    for (int ct2 = 0; ct2 < 2; ++ct2) {
      float bias = b1l[fc0 + w * 32 + ct2 * 16 + m];
#pragma unroll
      for (int r = 0; r < 4; ++r)
        s_hw[(q * 4 + r) * 44 + ct2 * 16 + m] = f2bf(fmaxf(acc1[ct2][r] + bias, 0.f));
    }
    // FFN2 over this wave's 32-wide k-slice (all wave-private LDS)
    bf16x8 a2 = *reinterpret_cast<const bf16x8*>(&s_hw[m * 44 + q * 8]);
#pragma unroll
    for (int ct = 0; ct < 5; ++ct) {
      bf16x8 b = *reinterpret_cast<const bf16x8*>(&s_w2w[(ct * 16 + m) * 40 + q * 8]);
      acc2[ct] = __builtin_amdgcn_mfma_f32_16x16x32_bf16(a2, b, acc2[ct], 0, 0, 0);
    }
  }
  __syncthreads();  // all waves done with w1 slices; s_red may overwrite
#pragma unroll
  for (int ct = 0; ct < 5; ++ct)
#pragma unroll
    for (int r = 0; r < 4; ++r)
      s_red[w * 1280 + (q * 4 + r) * 80 + ct * 16 + m] = acc2[ct][r];
  __syncthreads();
  for (int e = tid; e < 800; e += 256) {
    int row = e / 80, cc = e % 80;
    float v = s_red[row * 80 + cc] + s_red[1280 + row * 80 + cc] +
              s_red[2560 + row * 80 + cc] + s_red[3840 + row * 80 + cc];
    v += b2l[cc] + s_res[row * 80 + cc];
    s_val[e] = v;
  }
  __syncthreads();
  if (tid < 80) {
    int rr = tid >> 3, t8 = tid & 7;
    float sm = 0.f, sq = 0.f;
    for (int d = t8 * 10; d < t8 * 10 + 10; ++d) {
      float v = s_val[rr * 80 + d];
      sm += v; sq += v * v;
    }
    for (int mm = 4; mm >= 1; mm >>= 1) {
      sm += __shfl_xor(sm, mm, 8);
      sq += __shfl_xor(sq, mm, 8);
    }
    if (t8 == 0) {
      float mu = sm * (1.f / DD);
      s_mu2[rr] = mu;
      s_ri2[rr] = rsqrtf(sq * (1.f / DD) - mu * mu + EPSF);
    }
  }
  __syncthreads();
  for (int e = tid; e < 800; e += 256) {
    int row = e / 80, cc = e % 80;
    float xv = (s_val[e] - s_mu2[row]) * s_ri2[row] * ogl[cc] + obl[cc];
    x[(r0 + row) * DD + cc] = xv;
    s_val[e] = xv;                     // keep x rows in LDS for qkv(l+1)
  }
  // ---- fused QKV(l+1): row-local LN_in + GEMM over own 10 rows ----
  if (do_qkv) {
    __syncthreads();
    if (tid < 80) {
      int rr = tid >> 3, t8 = tid & 7;
      float sm = 0.f, sq = 0.f;
      for (int d = t8 * 10; d < t8 * 10 + 10; ++d) {
        float v = s_val[rr * 80 + d];
        sm += v; sq += v * v;
      }
      for (int mm = 4; mm >= 1; mm >>= 1) {
        sm += __shfl_xor(sm, mm, 8);
        sq += __shfl_xor(sq, mm, 8);
      }
      if (t8 == 0) {
        float mu = sm * (1.f / DD);
        s_mu2[rr] = mu;
        s_ri2[rr] = rsqrtf(sq * (1.f / DD) - mu * mu + EPSF);
      }
    }
    __syncthreads();
    for (int e = tid; e < 800; e += 256) {
      int row = e / 80, cc = e % 80;
      s_val[e] = (s_val[e] - s_mu2[row]) * s_ri2[row] * lng_n[cc] + lnb_n[cc];
    }
    __syncthreads();
    if (tid < 240) {
      const float* Wn;
      float bn;
      if (tid < 80) {
        Wn = Wq_n + tid * DD;
        bn = bq_n[tid];
      } else {
        Wn = Wkv_n + (tid - 80) * DD;
        bn = bkv_n[tid - 80];
      }
      float acc[10] = {};
      for (int d4 = 0; d4 < 20; ++d4) {
        float4 wv = *reinterpret_cast<const float4*>(&Wn[d4 * 4]);
#pragma unroll
        for (int r = 0; r < 10; ++r) {
          float4 sv = *reinterpret_cast<const float4*>(&s_val[r * 80 + d4 * 4]);
          acc[r] += sv.x * wv.x + sv.y * wv.y + sv.z * wv.z + sv.w * wv.w;
        }
      }
#pragma unroll
      for (int r = 0; r < 10; ++r)
        qkv[(r0 + r) * 240 + tid] = acc[r] + bn;
    }
  }
}

// ---------------- P: final projection + lengths tail ----------------
__global__ __launch_bounds__(256) void k_proj(
    const float* __restrict__ x, const float* __restrict__ Wp,
    const float* __restrict__ bp, const int* __restrict__ lengths,
    float* __restrict__ out) {
  __shared__ float s_a[64 * 84], s_w[64 * 84];
  int tid = threadIdx.x;
  int gr0 = blockIdx.x * 64;
  int c0 = blockIdx.y * 64;
  int b = gr0 / UU;
  int u0 = gr0 % UU;
  for (int k = 0; k < 5; ++k) {
    int idx = tid + k * 256;
    int row = idx / 20, c4 = idx % 20;
    *reinterpret_cast<float4*>(&s_a[row * 84 + c4 * 4]) =
        *reinterpret_cast<const float4*>(&x[(b * KK + RCL + u0 + row) * DD + c4 * 4]);
    *reinterpret_cast<float4*>(&s_w[row * 84 + c4 * 4]) =
        *reinterpret_cast<const float4*>(&Wp[(c0 + row) * DD + c4 * 4]);
  }
  __syncthreads();
  int ty = tid >> 4, tx = tid & 15;
  float acc[4][4] = {};
  for (int d4 = 0; d4 < 20; ++d4) {
    float4 a[4], w[4];
#pragma unroll
    for (int i2 = 0; i2 < 4; ++i2)
      a[i2] = *reinterpret_cast<const float4*>(&s_a[(4 * ty + i2) * 84 + d4 * 4]);
#pragma unroll
    for (int j = 0; j < 4; ++j)
      w[j] = *reinterpret_cast<const float4*>(&s_w[(tx + 16 * j) * 84 + d4 * 4]);
#pragma unroll
    for (int i2 = 0; i2 < 4; ++i2)
#pragma unroll
      for (int j = 0; j < 4; ++j)
        acc[i2][j] += a[i2].x * w[j].x + a[i2].y * w[j].y +
                      a[i2].z * w[j].z + a[i2].w * w[j].w;
  }
  for (int i2 = 0; i2 < 4; ++i2)
    for (int j = 0; j < 4; ++j) {
      int c = c0 + tx + 16 * j;
      out[(gr0 + 4 * ty + i2) * OUTD + c] = acc[i2][j] + bp[c];
    }
  if (blockIdx.x == 0 && blockIdx.y == 0 && tid < BB)
    out[BB * UU * OUTD + tid] = (float)lengths[tid];
}

extern "C" void kernel_launch(void* const* d_in, const int* in_sizes, int n_in,
                              void* d_out, int out_size, void* d_ws, size_t ws_size,
                              hipStream_t stream) {
  const float* mel   = (const float*)d_in[0];
  const float* lng   = (const float*)d_in[1];
  const float* lnb   = (const float*)d_in[2];
  const float* Wq    = (const float*)d_in[3];
  const float* bq    = (const float*)d_in[4];
  const float* Wkv   = (const float*)d_in[5];
  const float* bkv   = (const float*)d_in[6];
  const float* Wo    = (const float*)d_in[7];
  const float* bo    = (const float*)d_in[8];
  const float* ffg   = (const float*)d_in[9];
  const float* ffb   = (const float*)d_in[10];
  const float* W1    = (const float*)d_in[11];
  const float* b1    = (const float*)d_in[12];
  const float* W2    = (const float*)d_in[13];
  const float* b2    = (const float*)d_in[14];
  const float* og    = (const float*)d_in[15];
  const float* ob    = (const float*)d_in[16];
  const float* Wp    = (const float*)d_in[17];
  const float* bp    = (const float*)d_in[18];
  const int*   lens  = (const int*)d_in[19];
  float* out = (float*)d_out;

  float* ws = (float*)d_ws;
  float* x    = ws;                        // ROWS*DD
  float* qkv  = x + ROWS * DD;             // ROWS*240
  float* attn = qkv + ROWS * 240;          // ROWS*DD
  unsigned short* w1bf = (unsigned short*)(attn + ROWS * DD);  // LL*FFND*DD bf16
  unsigned short* w2bf = w1bf + LL * FFND * DD;                // LL*FFND*DD bf16

  k_gather<<<(ROWS * DD + 255) / 256, 256, 0, stream>>>(mel, x);
  k_cvt<<<(2 * (LL * FFND * DD) / 4 + 255) / 256, 256, 0, stream>>>(W1, W2, w1bf, w2bf);
  k_qkv<<<dim3(ROWS / 32, 3), 256, 0, stream>>>(
      x, qkv, Wq, bq, Wkv, bkv, lng, lnb);

  for (int l = 0; l < LL; ++l) {
    int ln = (l < LL - 1) ? l + 1 : l;  // next-layer params (unused when l==11)
    k_attn<<<dim3(NSEG, HH, BB), 256, 0, stream>>>(qkv, attn, lens);
    k_fused<<<ROWS / 10, 256, 0, stream>>>(
        attn, x, qkv,
        Wo + l * DD * DD, bo + l * DD,
        ffg + l * DD, ffb + l * DD,
        w1bf + l * FFND * DD, b1 + l * FFND,
        w2bf + l * FFND * DD, b2 + l * DD,
        og + l * DD, ob + l * DD,
        lng + ln * DD, lnb + ln * DD,
        Wq + ln * DD * DD, bq + ln * DD,
        Wkv + ln * 2 * DD * DD, bkv + ln * 2 * DD,
        (l < LL - 1) ? 1 : 0);
  }

  k_proj<<<dim3(BB * UU / 64, OUTD / 64), 256, 0, stream>>>(x, Wp, bp, lens, out);
}